// Round 1
// baseline (5588.581 us; speedup 1.0000x reference)
//
#include <hip/hip_runtime.h>
#include <math.h>

#define NF  128
#define HID 16

// ---------------------------------------------------------------------------
// zero agg [N*HID] and cnt [N]
__global__ void zero_kernel(float* __restrict__ agg, float* __restrict__ cnt,
                            int n_agg, int n_cnt) {
    int i = blockIdx.x * blockDim.x + threadIdx.x;
    if (i < n_agg) agg[i] = 0.f;
    if (i < n_cnt) cnt[i] = 0.f;
}

// ---------------------------------------------------------------------------
// p = x @ wl, q = x @ wr   (x: [N,128], wl/wr: [128,16])
// block = 256 threads = 16 nodes x 16 out-features
__global__ __launch_bounds__(256) void gemm1_kernel(
    const float* __restrict__ x, const float* __restrict__ wl,
    const float* __restrict__ wr, float* __restrict__ p,
    float* __restrict__ q, int N)
{
    __shared__ float swl[NF * HID];
    __shared__ float swr[NF * HID];
    __shared__ float xs[16][132];   // pad 128->132: keeps 16B align, breaks bank aliasing

    int tid  = threadIdx.x;
    int base = blockIdx.x * 16;

    for (int i = tid; i < NF * HID; i += 256) { swl[i] = wl[i]; swr[i] = wr[i]; }
    for (int i = tid; i < 16 * NF; i += 256) {
        int r = i >> 7, c = i & 127;
        int node = base + r;
        xs[r][c] = (node < N) ? x[(size_t)node * NF + c] : 0.f;
    }
    __syncthreads();

    int r = tid >> 4, f = tid & 15;
    int node = base + r;
    if (node >= N) return;

    float accl = 0.f, accr = 0.f;
    #pragma unroll
    for (int k = 0; k < NF; ++k) {
        float xv = xs[r][k];
        accl += xv * swl[k * HID + f];
        accr += xv * swr[k * HID + f];
    }
    p[(size_t)node * HID + f] = accl;
    q[(size_t)node * HID + f] = accr;
}

// ---------------------------------------------------------------------------
// one thread per edge: agg[dst] += p[src]; cnt[dst] += 1 (optional)
__global__ __launch_bounds__(256) void scatter_kernel(
    const int* __restrict__ src, const int* __restrict__ dst,
    const float* __restrict__ p, float* __restrict__ agg,
    float* __restrict__ cnt, int E)
{
    int e = blockIdx.x * blockDim.x + threadIdx.x;
    if (e >= E) return;
    int s = src[e], d = dst[e];
    const float4* pv = (const float4*)(p + (size_t)s * HID);
    float4 v0 = pv[0], v1 = pv[1], v2 = pv[2], v3 = pv[3];
    float* ag = agg + (size_t)d * HID;
    atomicAdd(ag + 0,  v0.x); atomicAdd(ag + 1,  v0.y);
    atomicAdd(ag + 2,  v0.z); atomicAdd(ag + 3,  v0.w);
    atomicAdd(ag + 4,  v1.x); atomicAdd(ag + 5,  v1.y);
    atomicAdd(ag + 6,  v1.z); atomicAdd(ag + 7,  v1.w);
    atomicAdd(ag + 8,  v2.x); atomicAdd(ag + 9,  v2.y);
    atomicAdd(ag + 10, v2.z); atomicAdd(ag + 11, v2.w);
    atomicAdd(ag + 12, v3.x); atomicAdd(ag + 13, v3.y);
    atomicAdd(ag + 14, v3.z); atomicAdd(ag + 15, v3.w);
    if (cnt) atomicAdd(cnt + d, 1.f);
}

// ---------------------------------------------------------------------------
// h = relu(agg / max(cnt,1) + b + q); optionally re-zero agg for next layer
__global__ void finalize_kernel(const float* __restrict__ agg,
    const float* __restrict__ q, const float* __restrict__ b,
    const float* __restrict__ cnt, float* __restrict__ h,
    float* __restrict__ agg_zero, int N)
{
    int i = blockIdx.x * blockDim.x + threadIdx.x;
    if (i >= N * HID) return;
    int node = i >> 4, f = i & 15;
    float c = cnt[node];
    float scale = 1.f / fmaxf(c, 1.f);
    float v = agg[i] * scale + b[f] + q[i];
    h[i] = fmaxf(v, 0.f);
    if (agg_zero) agg_zero[i] = 0.f;
}

// ---------------------------------------------------------------------------
// p = h @ wl, q = h @ wr   (h: [N,16], wl/wr: [16,16])
__global__ __launch_bounds__(256) void gemm2_kernel(
    const float* __restrict__ h, const float* __restrict__ wl,
    const float* __restrict__ wr, float* __restrict__ p,
    float* __restrict__ q, int N)
{
    __shared__ float swl[HID * HID];
    __shared__ float swr[HID * HID];
    __shared__ float hs[256];

    int tid  = threadIdx.x;
    int base = blockIdx.x * 16;
    if (tid < HID * HID) { swl[tid] = wl[tid]; swr[tid] = wr[tid]; }
    int gi = base * HID + tid;          // 256 consecutive elements, coalesced
    hs[tid] = (gi < N * HID) ? h[gi] : 0.f;
    __syncthreads();

    int r = tid >> 4, f = tid & 15;
    int node = base + r;
    if (node >= N) return;

    float accl = 0.f, accr = 0.f;
    #pragma unroll
    for (int k = 0; k < HID; ++k) {
        float hv = hs[r * HID + k];
        accl += hv * swl[k * HID + f];
        accr += hv * swr[k * HID + f];
    }
    p[(size_t)node * HID + f] = accl;
    q[(size_t)node * HID + f] = accr;
}

// ---------------------------------------------------------------------------
// per-edge: concat(h[src],h[dst]) -> fc1+relu -> fc2 -> log_softmax
__global__ __launch_bounds__(256) void edge_mlp_kernel(
    const int* __restrict__ src, const int* __restrict__ dst,
    const float* __restrict__ h,
    const float* __restrict__ fc1w, const float* __restrict__ fc1b,
    const float* __restrict__ fc2w, const float* __restrict__ fc2b,
    float* __restrict__ out, int E)
{
    __shared__ float w1[32 * 16];
    __shared__ float b1[16];
    __shared__ float w2[32];
    __shared__ float b2[2];

    int tid = threadIdx.x;
    for (int i = tid; i < 512; i += 256) w1[i] = fc1w[i];
    if (tid < 16) b1[tid] = fc1b[tid];
    if (tid < 32) w2[tid] = fc2w[tid];
    if (tid < 2)  b2[tid] = fc2b[tid];
    __syncthreads();

    int e = blockIdx.x * blockDim.x + tid;
    if (e >= E) return;
    int s = src[e], d = dst[e];

    float feat[32];
    const float4* hs4 = (const float4*)(h + (size_t)s * HID);
    const float4* hd4 = (const float4*)(h + (size_t)d * HID);
    #pragma unroll
    for (int i = 0; i < 4; ++i) {
        float4 v = hs4[i];
        feat[4*i+0] = v.x; feat[4*i+1] = v.y; feat[4*i+2] = v.z; feat[4*i+3] = v.w;
    }
    #pragma unroll
    for (int i = 0; i < 4; ++i) {
        float4 v = hd4[i];
        feat[16+4*i+0] = v.x; feat[16+4*i+1] = v.y; feat[16+4*i+2] = v.z; feat[16+4*i+3] = v.w;
    }

    float z[16];
    #pragma unroll
    for (int j = 0; j < 16; ++j) z[j] = b1[j];
    #pragma unroll
    for (int i = 0; i < 32; ++i) {
        float fv = feat[i];
        #pragma unroll
        for (int j = 0; j < 16; ++j) z[j] += fv * w1[i * 16 + j];
    }

    float o0 = b2[0], o1 = b2[1];
    #pragma unroll
    for (int j = 0; j < 16; ++j) {
        float zj = fmaxf(z[j], 0.f);
        o0 += zj * w2[2 * j + 0];
        o1 += zj * w2[2 * j + 1];
    }

    float m = fmaxf(o0, o1);
    float lse = m + logf(expf(o0 - m) + expf(o1 - m));
    float2 res; res.x = o0 - lse; res.y = o1 - lse;
    ((float2*)out)[e] = res;
}

// ---------------------------------------------------------------------------
extern "C" void kernel_launch(void* const* d_in, const int* in_sizes, int n_in,
                              void* d_out, int out_size, void* d_ws, size_t ws_size,
                              hipStream_t stream)
{
    const float* x    = (const float*)d_in[0];
    const int*   ei   = (const int*)  d_in[1];
    const float* w1l  = (const float*)d_in[2];
    const float* b1l  = (const float*)d_in[3];
    const float* w1r  = (const float*)d_in[4];
    const float* w2l  = (const float*)d_in[5];
    const float* b2l  = (const float*)d_in[6];
    const float* w2r  = (const float*)d_in[7];
    const float* fc1w = (const float*)d_in[8];
    const float* fc1b = (const float*)d_in[9];
    const float* fc2w = (const float*)d_in[10];
    const float* fc2b = (const float*)d_in[11];
    float* out = (float*)d_out;

    int N = in_sizes[0] / NF;
    int E = in_sizes[1] / 2;
    const int* src = ei;
    const int* dst = ei + E;

    // workspace layout (floats): p | q | agg | h | cnt  -> ~26 MB
    float* p   = (float*)d_ws;
    float* q   = p   + (size_t)N * HID;
    float* agg = q   + (size_t)N * HID;
    float* h   = agg + (size_t)N * HID;
    float* cnt = h   + (size_t)N * HID;

    int nh = N * HID;

    zero_kernel<<<(nh + 255) / 256, 256, 0, stream>>>(agg, cnt, nh, N);

    // layer 1
    gemm1_kernel<<<(N + 15) / 16, 256, 0, stream>>>(x, w1l, w1r, p, q, N);
    scatter_kernel<<<(E + 255) / 256, 256, 0, stream>>>(src, dst, p, agg, cnt, E);
    finalize_kernel<<<(nh + 255) / 256, 256, 0, stream>>>(agg, q, b1l, cnt, h, agg, N);

    // layer 2 (agg was re-zeroed by finalize)
    gemm2_kernel<<<(N + 15) / 16, 256, 0, stream>>>(h, w2l, w2r, p, q, N);
    scatter_kernel<<<(E + 255) / 256, 256, 0, stream>>>(src, dst, p, agg, nullptr, E);
    finalize_kernel<<<(nh + 255) / 256, 256, 0, stream>>>(agg, q, b2l, cnt, h, nullptr, N);

    // edge MLP + log_softmax
    edge_mlp_kernel<<<(E + 255) / 256, 256, 0, stream>>>(src, dst, h, fc1w, fc1b,
                                                         fc2w, fc2b, out, E);
}

// Round 2
// 839.205 us; speedup vs baseline: 6.6594x; 6.6594x over previous
//
#include <hip/hip_runtime.h>
#include <math.h>

#define NF  128
#define HID 16

// ---------------------------------------------------------------------------
// zero cursor [N] (ws is poisoned 0xAA before every call)
__global__ void zero_kernel(int* __restrict__ cursor, int n) {
    int i = blockIdx.x * blockDim.x + threadIdx.x;
    if (i < n) cursor[i] = 0;
}

// ---------------------------------------------------------------------------
// degree histogram: cursor[dst[e]] += 1
__global__ __launch_bounds__(256) void hist_kernel(
    const int* __restrict__ dst, int* __restrict__ cursor, int E)
{
    int e = blockIdx.x * blockDim.x + threadIdx.x;
    if (e < E) atomicAdd(&cursor[dst[e]], 1);
}

// ---------------------------------------------------------------------------
// in-place 2-level exclusive scan over cursor[N]. Phase 1: per-block (256 thr
// x 4 items = 1024) exclusive scan + block totals.
__global__ __launch_bounds__(256) void scan1_kernel(
    int* __restrict__ data, int* __restrict__ blockSums, int N)
{
    __shared__ int s[256];
    int tid  = threadIdx.x;
    int base = blockIdx.x * 1024 + tid * 4;
    int v[4]; int sum = 0;
    #pragma unroll
    for (int k = 0; k < 4; ++k) {
        int i = base + k;
        v[k] = (i < N) ? data[i] : 0;
        sum += v[k];
    }
    s[tid] = sum;
    __syncthreads();
    for (int off = 1; off < 256; off <<= 1) {   // inclusive Hillis-Steele
        int t = (tid >= off) ? s[tid - off] : 0;
        __syncthreads();
        s[tid] += t;
        __syncthreads();
    }
    int run = s[tid] - sum;                      // exclusive prefix of this thread
    #pragma unroll
    for (int k = 0; k < 4; ++k) {
        int i = base + k;
        if (i < N) data[i] = run;
        run += v[k];
    }
    if (tid == 0) blockSums[blockIdx.x] = s[255];
}

// Phase 2: single-block exclusive scan of blockSums (nblk <= 256)
__global__ __launch_bounds__(256) void scan2_kernel(int* __restrict__ blockSums, int nblk)
{
    __shared__ int s[256];
    int tid = threadIdx.x;
    int v = (tid < nblk) ? blockSums[tid] : 0;
    s[tid] = v;
    __syncthreads();
    for (int off = 1; off < 256; off <<= 1) {
        int t = (tid >= off) ? s[tid - off] : 0;
        __syncthreads();
        s[tid] += t;
        __syncthreads();
    }
    if (tid < nblk) blockSums[tid] = s[tid] - v; // exclusive
}

// Phase 3: add block offsets back
__global__ __launch_bounds__(256) void scan3_kernel(
    int* __restrict__ data, const int* __restrict__ blockSums, int N)
{
    int off = blockSums[blockIdx.x];
    int base = blockIdx.x * 1024 + threadIdx.x * 4;
    #pragma unroll
    for (int k = 0; k < 4; ++k) {
        int i = base + k;
        if (i < N) data[i] += off;
    }
}

// ---------------------------------------------------------------------------
// fill CSR: pos = cursor[dst]++; esrc[pos] = src.
// After this pass cursor[n] == row_end(n); row_start(n) == (n? cursor[n-1] : 0)
__global__ __launch_bounds__(256) void fill_kernel(
    const int* __restrict__ src, const int* __restrict__ dst,
    int* __restrict__ cursor, int* __restrict__ esrc, int E)
{
    int e = blockIdx.x * blockDim.x + threadIdx.x;
    if (e >= E) return;
    int pos = atomicAdd(&cursor[dst[e]], 1);
    esrc[pos] = src[e];
}

// ---------------------------------------------------------------------------
// p = x @ wl, q = x @ wr   (x: [N,128], wl/wr: [128,16])
__global__ __launch_bounds__(256) void gemm1_kernel(
    const float* __restrict__ x, const float* __restrict__ wl,
    const float* __restrict__ wr, float* __restrict__ p,
    float* __restrict__ q, int N)
{
    __shared__ float swl[NF * HID];
    __shared__ float swr[NF * HID];
    __shared__ float xs[16][132];

    int tid  = threadIdx.x;
    int base = blockIdx.x * 16;

    for (int i = tid; i < NF * HID; i += 256) { swl[i] = wl[i]; swr[i] = wr[i]; }
    for (int i = tid; i < 16 * NF; i += 256) {
        int r = i >> 7, c = i & 127;
        int node = base + r;
        xs[r][c] = (node < N) ? x[(size_t)node * NF + c] : 0.f;
    }
    __syncthreads();

    int r = tid >> 4, f = tid & 15;
    int node = base + r;
    if (node >= N) return;

    float accl = 0.f, accr = 0.f;
    #pragma unroll
    for (int k = 0; k < NF; ++k) {
        float xv = xs[r][k];
        accl += xv * swl[k * HID + f];
        accr += xv * swr[k * HID + f];
    }
    p[(size_t)node * HID + f] = accl;
    q[(size_t)node * HID + f] = accr;
}

// ---------------------------------------------------------------------------
// p = h @ wl, q = h @ wr (16x16 weights). q may alias h (per-block tile is
// loaded to LDS before any write; blocks touch disjoint rows).
__global__ __launch_bounds__(256) void gemm2_kernel(
    const float* __restrict__ h, const float* __restrict__ wl,
    const float* __restrict__ wr, float* __restrict__ p,
    float* __restrict__ q, int N)
{
    __shared__ float swl[HID * HID];
    __shared__ float swr[HID * HID];
    __shared__ float hs[256];

    int tid  = threadIdx.x;
    int base = blockIdx.x * 16;
    if (tid < HID * HID) { swl[tid] = wl[tid]; swr[tid] = wr[tid]; }
    int gi = base * HID + tid;
    hs[tid] = (gi < N * HID) ? h[gi] : 0.f;
    __syncthreads();

    int r = tid >> 4, f = tid & 15;
    int node = base + r;
    if (node >= N) return;

    float accl = 0.f, accr = 0.f;
    #pragma unroll
    for (int k = 0; k < HID; ++k) {
        float hv = hs[r * HID + k];
        accl += hv * swl[k * HID + f];
        accr += hv * swr[k * HID + f];
    }
    p[(size_t)node * HID + f] = accl;
    q[(size_t)node * HID + f] = accr;
}

// ---------------------------------------------------------------------------
// gather-aggregate + fused finalize: one wave per node.
// lane = j*16 + f (j: 4 edges in flight, f: feature).
// h[n,f] = relu( sum_{e in N(n)} p[esrc[e],f] / max(deg,1) + b[f] + q[n,f] )
// h may alias q (each lane reads/writes only its own node's row).
__global__ __launch_bounds__(256) void aggregate_kernel(
    const int* __restrict__ cursor, const int* __restrict__ esrc,
    const float* __restrict__ p, const float* __restrict__ q,
    const float* __restrict__ b, float* __restrict__ h, int N)
{
    int gt   = blockIdx.x * blockDim.x + threadIdx.x;
    int node = gt >> 6;
    int lane = threadIdx.x & 63;
    if (node >= N) return;

    int end   = cursor[node];
    int start = (node == 0) ? 0 : cursor[node - 1];
    int f = lane & 15, j = lane >> 4;

    float acc = 0.f;
    for (int e = start + j; e < end; e += 4) {
        int s = esrc[e];
        acc += p[(size_t)s * HID + f];
    }
    acc += __shfl_xor(acc, 16);
    acc += __shfl_xor(acc, 32);

    if (j == 0) {
        float deg = (float)(end - start);
        float v = acc / fmaxf(deg, 1.f) + b[f] + q[(size_t)node * HID + f];
        h[(size_t)node * HID + f] = fmaxf(v, 0.f);
    }
}

// ---------------------------------------------------------------------------
// per-edge: concat(h[src],h[dst]) -> fc1+relu -> fc2 -> log_softmax
__global__ __launch_bounds__(256) void edge_mlp_kernel(
    const int* __restrict__ src, const int* __restrict__ dst,
    const float* __restrict__ h,
    const float* __restrict__ fc1w, const float* __restrict__ fc1b,
    const float* __restrict__ fc2w, const float* __restrict__ fc2b,
    float* __restrict__ out, int E)
{
    __shared__ float w1[32 * 16];
    __shared__ float b1[16];
    __shared__ float w2[32];
    __shared__ float b2[2];

    int tid = threadIdx.x;
    for (int i = tid; i < 512; i += 256) w1[i] = fc1w[i];
    if (tid < 16) b1[tid] = fc1b[tid];
    if (tid < 32) w2[tid] = fc2w[tid];
    if (tid < 2)  b2[tid] = fc2b[tid];
    __syncthreads();

    int e = blockIdx.x * blockDim.x + tid;
    if (e >= E) return;
    int s = src[e], d = dst[e];

    float feat[32];
    const float4* hs4 = (const float4*)(h + (size_t)s * HID);
    const float4* hd4 = (const float4*)(h + (size_t)d * HID);
    #pragma unroll
    for (int i = 0; i < 4; ++i) {
        float4 v = hs4[i];
        feat[4*i+0] = v.x; feat[4*i+1] = v.y; feat[4*i+2] = v.z; feat[4*i+3] = v.w;
    }
    #pragma unroll
    for (int i = 0; i < 4; ++i) {
        float4 v = hd4[i];
        feat[16+4*i+0] = v.x; feat[16+4*i+1] = v.y; feat[16+4*i+2] = v.z; feat[16+4*i+3] = v.w;
    }

    float z[16];
    #pragma unroll
    for (int j = 0; j < 16; ++j) z[j] = b1[j];
    #pragma unroll
    for (int i = 0; i < 32; ++i) {
        float fv = feat[i];
        #pragma unroll
        for (int j = 0; j < 16; ++j) z[j] += fv * w1[i * 16 + j];
    }

    float o0 = b2[0], o1 = b2[1];
    #pragma unroll
    for (int j = 0; j < 16; ++j) {
        float zj = fmaxf(z[j], 0.f);
        o0 += zj * w2[2 * j + 0];
        o1 += zj * w2[2 * j + 1];
    }

    float m = fmaxf(o0, o1);
    float lse = m + logf(expf(o0 - m) + expf(o1 - m));
    float2 res; res.x = o0 - lse; res.y = o1 - lse;
    ((float2*)out)[e] = res;
}

// ---------------------------------------------------------------------------
extern "C" void kernel_launch(void* const* d_in, const int* in_sizes, int n_in,
                              void* d_out, int out_size, void* d_ws, size_t ws_size,
                              hipStream_t stream)
{
    const float* x    = (const float*)d_in[0];
    const int*   ei   = (const int*)  d_in[1];
    const float* w1l  = (const float*)d_in[2];
    const float* b1l  = (const float*)d_in[3];
    const float* w1r  = (const float*)d_in[4];
    const float* w2l  = (const float*)d_in[5];
    const float* b2l  = (const float*)d_in[6];
    const float* w2r  = (const float*)d_in[7];
    const float* fc1w = (const float*)d_in[8];
    const float* fc1b = (const float*)d_in[9];
    const float* fc2w = (const float*)d_in[10];
    const float* fc2b = (const float*)d_in[11];
    float* out = (float*)d_out;

    int N = in_sizes[0] / NF;
    int E = in_sizes[1] / 2;
    const int* src = ei;
    const int* dst = ei + E;

    // ws layout (all 4B types): A[N*16] f32 | B[N*16] f32 | esrc[E] i32 |
    //                           cursor[N] i32 | blockSums[256] i32   (~26 MB)
    float* A      = (float*)d_ws;
    float* B      = A + (size_t)N * HID;
    int*   esrc   = (int*)(B + (size_t)N * HID);
    int*   cursor = esrc + E;
    int*   bsums  = cursor + N;

    int nblk = (N + 1023) / 1024;   // 98 for N=100000, must be <= 256

    // ---- CSR build (once, reused by both layers) ----
    zero_kernel<<<(N + 255) / 256, 256, 0, stream>>>(cursor, N);
    hist_kernel<<<(E + 255) / 256, 256, 0, stream>>>(dst, cursor, E);
    scan1_kernel<<<nblk, 256, 0, stream>>>(cursor, bsums, N);
    scan2_kernel<<<1, 256, 0, stream>>>(bsums, nblk);
    scan3_kernel<<<nblk, 256, 0, stream>>>(cursor, bsums, N);
    fill_kernel<<<(E + 255) / 256, 256, 0, stream>>>(src, dst, cursor, esrc, E);

    int aggBlocks = (int)(((size_t)N * 64 + 255) / 256);

    // ---- layer 1: p->A, q->B; aggregate writes h1 into B (in-place) ----
    gemm1_kernel<<<(N + 15) / 16, 256, 0, stream>>>(x, w1l, w1r, A, B, N);
    aggregate_kernel<<<aggBlocks, 256, 0, stream>>>(cursor, esrc, A, B, b1l, B, N);

    // ---- layer 2: reads B, p->A, q->B (in-place); h2 into B ----
    gemm2_kernel<<<(N + 15) / 16, 256, 0, stream>>>(B, w2l, w2r, A, B, N);
    aggregate_kernel<<<aggBlocks, 256, 0, stream>>>(cursor, esrc, A, B, b2l, B, N);

    // ---- edge MLP + log_softmax ----
    edge_mlp_kernel<<<(E + 255) / 256, 256, 0, stream>>>(src, dst, B, fc1w, fc1b,
                                                         fc2w, fc2b, out, E);
}

// Round 3
// 696.362 us; speedup vs baseline: 8.0254x; 1.2051x over previous
//
#include <hip/hip_runtime.h>
#include <math.h>

#define NF  128
#define HID 16

// ---------------------------------------------------------------------------
// head[i] = -1 (ws is poisoned 0xAA before every call)
__global__ void init_head_kernel(int* __restrict__ head, int n) {
    int i = blockIdx.x * blockDim.x + threadIdx.x;
    if (i < n) head[i] = -1;
}

// ---------------------------------------------------------------------------
// lock-free per-dst linked list: next[e] = atomicExch(&head[dst[e]], e)
// next[] writes are coalesced (indexed by e); only head atomics are scattered.
__global__ __launch_bounds__(256) void link_kernel(
    const int* __restrict__ dst, int* __restrict__ head,
    int* __restrict__ next, int E)
{
    int e = blockIdx.x * blockDim.x + threadIdx.x;
    if (e >= E) return;
    next[e] = atomicExch(&head[dst[e]], e);
}

// ---------------------------------------------------------------------------
// p = x @ wl, q = x @ wr   (x: [N,128], wl/wr: [128,16])
__global__ __launch_bounds__(256) void gemm1_kernel(
    const float* __restrict__ x, const float* __restrict__ wl,
    const float* __restrict__ wr, float* __restrict__ p,
    float* __restrict__ q, int N)
{
    __shared__ float swl[NF * HID];
    __shared__ float swr[NF * HID];
    __shared__ float xs[16][132];

    int tid  = threadIdx.x;
    int base = blockIdx.x * 16;

    for (int i = tid; i < NF * HID; i += 256) { swl[i] = wl[i]; swr[i] = wr[i]; }
    for (int i = tid; i < 16 * NF; i += 256) {
        int r = i >> 7, c = i & 127;
        int node = base + r;
        xs[r][c] = (node < N) ? x[(size_t)node * NF + c] : 0.f;
    }
    __syncthreads();

    int r = tid >> 4, f = tid & 15;
    int node = base + r;
    if (node >= N) return;

    float accl = 0.f, accr = 0.f;
    #pragma unroll
    for (int k = 0; k < NF; ++k) {
        float xv = xs[r][k];
        accl += xv * swl[k * HID + f];
        accr += xv * swr[k * HID + f];
    }
    p[(size_t)node * HID + f] = accl;
    q[(size_t)node * HID + f] = accr;
}

// ---------------------------------------------------------------------------
// p = h @ wl, q = h @ wr (16x16 weights). q may alias h (per-block tile is
// loaded to LDS before any write; blocks touch disjoint rows).
__global__ __launch_bounds__(256) void gemm2_kernel(
    const float* __restrict__ h, const float* __restrict__ wl,
    const float* __restrict__ wr, float* __restrict__ p,
    float* __restrict__ q, int N)
{
    __shared__ float swl[HID * HID];
    __shared__ float swr[HID * HID];
    __shared__ float hs[256];

    int tid  = threadIdx.x;
    int base = blockIdx.x * 16;
    if (tid < HID * HID) { swl[tid] = wl[tid]; swr[tid] = wr[tid]; }
    int gi = base * HID + tid;
    hs[tid] = (gi < N * HID) ? h[gi] : 0.f;
    __syncthreads();

    int r = tid >> 4, f = tid & 15;
    int node = base + r;
    if (node >= N) return;

    float accl = 0.f, accr = 0.f;
    #pragma unroll
    for (int k = 0; k < HID; ++k) {
        float hv = hs[r * HID + k];
        accl += hv * swl[k * HID + f];
        accr += hv * swr[k * HID + f];
    }
    p[(size_t)node * HID + f] = accl;
    q[(size_t)node * HID + f] = accr;
}

// ---------------------------------------------------------------------------
// chain-walk aggregate + fused finalize. 16 lanes per node (lane = feature).
// h[n,f] = relu( mean_{e in chain(n)} p[src[e],f] + b[f] + q[n,f] )
// h may alias q (each thread reads its own q element before writing h).
__global__ __launch_bounds__(256) void aggregate_kernel(
    const int* __restrict__ head, const int* __restrict__ next,
    const int* __restrict__ src,
    const float* __restrict__ p, const float* __restrict__ q,
    const float* __restrict__ b, float* __restrict__ h, int N)
{
    int gt   = blockIdx.x * blockDim.x + threadIdx.x;
    int node = gt >> 4;
    int f    = threadIdx.x & 15;
    if (node >= N) return;

    float acc = 0.f;
    int deg = 0;
    int e = head[node];
    while (e >= 0) {
        int s = src[e];                    // 16-lane broadcast load (L2)
        acc += p[(size_t)s * HID + f];     // contiguous 64B row (L2)
        ++deg;
        e = next[e];                       // serial chain dependency (L2)
    }

    float v = acc / fmaxf((float)deg, 1.f) + b[f] + q[(size_t)node * HID + f];
    h[(size_t)node * HID + f] = fmaxf(v, 0.f);
}

// ---------------------------------------------------------------------------
// per-edge: concat(h[src],h[dst]) -> fc1+relu -> fc2 -> log_softmax
__global__ __launch_bounds__(256) void edge_mlp_kernel(
    const int* __restrict__ src, const int* __restrict__ dst,
    const float* __restrict__ h,
    const float* __restrict__ fc1w, const float* __restrict__ fc1b,
    const float* __restrict__ fc2w, const float* __restrict__ fc2b,
    float* __restrict__ out, int E)
{
    __shared__ float w1[32 * 16];
    __shared__ float b1[16];
    __shared__ float w2[32];
    __shared__ float b2[2];

    int tid = threadIdx.x;
    for (int i = tid; i < 512; i += 256) w1[i] = fc1w[i];
    if (tid < 16) b1[tid] = fc1b[tid];
    if (tid < 32) w2[tid] = fc2w[tid];
    if (tid < 2)  b2[tid] = fc2b[tid];
    __syncthreads();

    int e = blockIdx.x * blockDim.x + tid;
    if (e >= E) return;
    int s = src[e], d = dst[e];

    float feat[32];
    const float4* hs4 = (const float4*)(h + (size_t)s * HID);
    const float4* hd4 = (const float4*)(h + (size_t)d * HID);
    #pragma unroll
    for (int i = 0; i < 4; ++i) {
        float4 v = hs4[i];
        feat[4*i+0] = v.x; feat[4*i+1] = v.y; feat[4*i+2] = v.z; feat[4*i+3] = v.w;
    }
    #pragma unroll
    for (int i = 0; i < 4; ++i) {
        float4 v = hd4[i];
        feat[16+4*i+0] = v.x; feat[16+4*i+1] = v.y; feat[16+4*i+2] = v.z; feat[16+4*i+3] = v.w;
    }

    float z[16];
    #pragma unroll
    for (int j = 0; j < 16; ++j) z[j] = b1[j];
    #pragma unroll
    for (int i = 0; i < 32; ++i) {
        float fv = feat[i];
        #pragma unroll
        for (int j = 0; j < 16; ++j) z[j] += fv * w1[i * 16 + j];
    }

    float o0 = b2[0], o1 = b2[1];
    #pragma unroll
    for (int j = 0; j < 16; ++j) {
        float zj = fmaxf(z[j], 0.f);
        o0 += zj * w2[2 * j + 0];
        o1 += zj * w2[2 * j + 1];
    }

    float m = fmaxf(o0, o1);
    float lse = m + logf(expf(o0 - m) + expf(o1 - m));
    float2 res; res.x = o0 - lse; res.y = o1 - lse;
    ((float2*)out)[e] = res;
}

// ---------------------------------------------------------------------------
extern "C" void kernel_launch(void* const* d_in, const int* in_sizes, int n_in,
                              void* d_out, int out_size, void* d_ws, size_t ws_size,
                              hipStream_t stream)
{
    const float* x    = (const float*)d_in[0];
    const int*   ei   = (const int*)  d_in[1];
    const float* w1l  = (const float*)d_in[2];
    const float* b1l  = (const float*)d_in[3];
    const float* w1r  = (const float*)d_in[4];
    const float* w2l  = (const float*)d_in[5];
    const float* b2l  = (const float*)d_in[6];
    const float* w2r  = (const float*)d_in[7];
    const float* fc1w = (const float*)d_in[8];
    const float* fc1b = (const float*)d_in[9];
    const float* fc2w = (const float*)d_in[10];
    const float* fc2b = (const float*)d_in[11];
    float* out = (float*)d_out;

    int N = in_sizes[0] / NF;
    int E = in_sizes[1] / 2;
    const int* src = ei;
    const int* dst = ei + E;

    // ws layout: A[N*16] f32 | B[N*16] f32 | next[E] i32 | head[N] i32  (~26 MB)
    float* A    = (float*)d_ws;
    float* B    = A + (size_t)N * HID;
    int*   next = (int*)(B + (size_t)N * HID);
    int*   head = next + E;

    // ---- linked-list "CSR" build (once, reused by both layers) ----
    init_head_kernel<<<(N + 255) / 256, 256, 0, stream>>>(head, N);
    link_kernel<<<(E + 255) / 256, 256, 0, stream>>>(dst, head, next, E);

    int aggBlocks = (int)(((size_t)N * 16 + 255) / 256);

    // ---- layer 1: p->A, q->B; aggregate writes h1 into B (in-place) ----
    gemm1_kernel<<<(N + 15) / 16, 256, 0, stream>>>(x, w1l, w1r, A, B, N);
    aggregate_kernel<<<aggBlocks, 256, 0, stream>>>(head, next, src, A, B, b1l, B, N);

    // ---- layer 2: reads B, p->A, q->B (in-place); h2 into B ----
    gemm2_kernel<<<(N + 15) / 16, 256, 0, stream>>>(B, w2l, w2r, A, B, N);
    aggregate_kernel<<<aggBlocks, 256, 0, stream>>>(head, next, src, A, B, b2l, B, N);

    // ---- edge MLP + log_softmax ----
    edge_mlp_kernel<<<(E + 255) / 256, 256, 0, stream>>>(src, dst, B, fc1w, fc1b,
                                                         fc2w, fc2b, out, E);
}

// Round 4
// 567.552 us; speedup vs baseline: 9.8468x; 1.2270x over previous
//
#include <hip/hip_runtime.h>
#include <hip/hip_fp16.h>
#include <math.h>

#define NF  128
#define HID 16

// ---------------------------------------------------------------------------
// head[i] = -1 (ws is poisoned 0xAA before every call)
__global__ void init_head_kernel(int* __restrict__ head, int n) {
    int i = blockIdx.x * blockDim.x + threadIdx.x;
    if (i < n) head[i] = -1;
}

// ---------------------------------------------------------------------------
// lock-free per-dst linked list, PACKED: next2[e] = (old_head, src[e])
// next2 writes coalesced (25.6 MB); only the head atomicExch is scattered.
__global__ __launch_bounds__(256) void link_packed_kernel(
    const int* __restrict__ src, const int* __restrict__ dst,
    int* __restrict__ head, int2* __restrict__ next2, int E)
{
    int e = blockIdx.x * blockDim.x + threadIdx.x;
    if (e >= E) return;
    int old = atomicExch(&head[dst[e]], e);
    next2[e] = make_int2(old, src[e]);
}

// unpacked fallback (smaller ws): next only; src read from input at walk time
__global__ __launch_bounds__(256) void link_kernel(
    const int* __restrict__ dst, int* __restrict__ head,
    int* __restrict__ next, int E)
{
    int e = blockIdx.x * blockDim.x + threadIdx.x;
    if (e >= E) return;
    next[e] = atomicExch(&head[dst[e]], e);
}

// ---------------------------------------------------------------------------
// p16 = x @ wl, q16 = x @ wr   (x: [N,128] f32, wl/wr: [128,16] f32, out fp16)
__global__ __launch_bounds__(256) void gemm1_kernel(
    const float* __restrict__ x, const float* __restrict__ wl,
    const float* __restrict__ wr, __half* __restrict__ p,
    __half* __restrict__ q, int N)
{
    __shared__ float swl[NF * HID];
    __shared__ float swr[NF * HID];
    __shared__ float xs[16][132];

    int tid  = threadIdx.x;
    int base = blockIdx.x * 16;

    for (int i = tid; i < NF * HID; i += 256) { swl[i] = wl[i]; swr[i] = wr[i]; }
    for (int i = tid; i < 16 * NF; i += 256) {
        int r = i >> 7, c = i & 127;
        int node = base + r;
        xs[r][c] = (node < N) ? x[(size_t)node * NF + c] : 0.f;
    }
    __syncthreads();

    int r = tid >> 4, f = tid & 15;
    int node = base + r;
    if (node >= N) return;

    float accl = 0.f, accr = 0.f;
    #pragma unroll
    for (int k = 0; k < NF; ++k) {
        float xv = xs[r][k];
        accl += xv * swl[k * HID + f];
        accr += xv * swr[k * HID + f];
    }
    p[(size_t)node * HID + f] = __float2half(accl);
    q[(size_t)node * HID + f] = __float2half(accr);
}

// ---------------------------------------------------------------------------
// p16 = h16 @ wl, q16 = h16 @ wr (16x16 fp32 weights; fp16 in/out, fp32 acc).
// q may alias h (tile staged in LDS before writes; blocks disjoint).
__global__ __launch_bounds__(256) void gemm2_kernel(
    const __half* __restrict__ h, const float* __restrict__ wl,
    const float* __restrict__ wr, __half* __restrict__ p,
    __half* __restrict__ q, int N)
{
    __shared__ float swl[HID * HID];
    __shared__ float swr[HID * HID];
    __shared__ float hs[256];

    int tid  = threadIdx.x;
    int base = blockIdx.x * 16;
    if (tid < HID * HID) { swl[tid] = wl[tid]; swr[tid] = wr[tid]; }
    int gi = base * HID + tid;                   // 256 consecutive halves
    hs[tid] = (gi < N * HID) ? __half2float(h[gi]) : 0.f;
    __syncthreads();

    int r = tid >> 4, f = tid & 15;
    int node = base + r;
    if (node >= N) return;

    float accl = 0.f, accr = 0.f;
    #pragma unroll
    for (int k = 0; k < HID; ++k) {
        float hv = hs[r * HID + k];
        accl += hv * swl[k * HID + f];
        accr += hv * swr[k * HID + f];
    }
    p[(size_t)node * HID + f] = __float2half(accl);
    q[(size_t)node * HID + f] = __float2half(accr);
}

// ---------------------------------------------------------------------------
// chain-walk aggregate, 8 lanes/node, half2 per lane (features 2j, 2j+1).
// h[n,:] = relu( mean p16[src,:] + b + q16[n,:] );  h may alias q.
__global__ __launch_bounds__(256) void aggregate_packed_kernel(
    const int* __restrict__ head, const int2* __restrict__ next2,
    const __half* __restrict__ p, const __half* __restrict__ q,
    const float* __restrict__ b, __half* __restrict__ h, int N)
{
    int gt   = blockIdx.x * blockDim.x + threadIdx.x;
    int node = gt >> 3;
    int j    = threadIdx.x & 7;
    if (node >= N) return;

    float2 acc = make_float2(0.f, 0.f);
    int deg = 0;
    int e = head[node];
    while (e >= 0) {
        int2 nx = next2[e];                       // one 8B line-hit per step
        float2 v = __half22float2(((const __half2*)(p + (size_t)nx.y * HID))[j]);
        acc.x += v.x; acc.y += v.y;
        ++deg;
        e = nx.x;
    }

    float inv = 1.f / fmaxf((float)deg, 1.f);
    float2 bb = ((const float2*)b)[j];
    float2 qq = __half22float2(((const __half2*)(q + (size_t)node * HID))[j]);
    float2 r;
    r.x = fmaxf(acc.x * inv + bb.x + qq.x, 0.f);
    r.y = fmaxf(acc.y * inv + bb.y + qq.y, 0.f);
    ((__half2*)(h + (size_t)node * HID))[j] = __floats2half2_rn(r.x, r.y);
}

// unpacked fallback: next + src separate
__global__ __launch_bounds__(256) void aggregate_chain_kernel(
    const int* __restrict__ head, const int* __restrict__ next,
    const int* __restrict__ src,
    const __half* __restrict__ p, const __half* __restrict__ q,
    const float* __restrict__ b, __half* __restrict__ h, int N)
{
    int gt   = blockIdx.x * blockDim.x + threadIdx.x;
    int node = gt >> 3;
    int j    = threadIdx.x & 7;
    if (node >= N) return;

    float2 acc = make_float2(0.f, 0.f);
    int deg = 0;
    int e = head[node];
    while (e >= 0) {
        int s = src[e];
        float2 v = __half22float2(((const __half2*)(p + (size_t)s * HID))[j]);
        acc.x += v.x; acc.y += v.y;
        ++deg;
        e = next[e];
    }

    float inv = 1.f / fmaxf((float)deg, 1.f);
    float2 bb = ((const float2*)b)[j];
    float2 qq = __half22float2(((const __half2*)(q + (size_t)node * HID))[j]);
    float2 r;
    r.x = fmaxf(acc.x * inv + bb.x + qq.x, 0.f);
    r.y = fmaxf(acc.y * inv + bb.y + qq.y, 0.f);
    ((__half2*)(h + (size_t)node * HID))[j] = __floats2half2_rn(r.x, r.y);
}

// ---------------------------------------------------------------------------
// per-edge: concat(h[src],h[dst]) -> fc1+relu -> fc2 -> log_softmax
__global__ __launch_bounds__(256) void edge_mlp_kernel(
    const int* __restrict__ src, const int* __restrict__ dst,
    const __half* __restrict__ h,
    const float* __restrict__ fc1w, const float* __restrict__ fc1b,
    const float* __restrict__ fc2w, const float* __restrict__ fc2b,
    float* __restrict__ out, int E)
{
    __shared__ float w1[32 * 16];
    __shared__ float b1[16];
    __shared__ float w2[32];
    __shared__ float b2[2];

    int tid = threadIdx.x;
    for (int i = tid; i < 512; i += 256) w1[i] = fc1w[i];
    if (tid < 16) b1[tid] = fc1b[tid];
    if (tid < 32) w2[tid] = fc2w[tid];
    if (tid < 2)  b2[tid] = fc2b[tid];
    __syncthreads();

    int e = blockIdx.x * blockDim.x + tid;
    if (e >= E) return;
    int s = src[e], d = dst[e];

    float feat[32];
    const __half2* hs2 = (const __half2*)(h + (size_t)s * HID);
    const __half2* hd2 = (const __half2*)(h + (size_t)d * HID);
    #pragma unroll
    for (int i = 0; i < 8; ++i) {
        float2 v = __half22float2(hs2[i]);
        feat[2*i+0] = v.x; feat[2*i+1] = v.y;
    }
    #pragma unroll
    for (int i = 0; i < 8; ++i) {
        float2 v = __half22float2(hd2[i]);
        feat[16+2*i+0] = v.x; feat[16+2*i+1] = v.y;
    }

    float z[16];
    #pragma unroll
    for (int j = 0; j < 16; ++j) z[j] = b1[j];
    #pragma unroll
    for (int i = 0; i < 32; ++i) {
        float fv = feat[i];
        #pragma unroll
        for (int j = 0; j < 16; ++j) z[j] += fv * w1[i * 16 + j];
    }

    float o0 = b2[0], o1 = b2[1];
    #pragma unroll
    for (int j = 0; j < 16; ++j) {
        float zj = fmaxf(z[j], 0.f);
        o0 += zj * w2[2 * j + 0];
        o1 += zj * w2[2 * j + 1];
    }

    float m = fmaxf(o0, o1);
    float lse = m + logf(expf(o0 - m) + expf(o1 - m));
    float2 res; res.x = o0 - lse; res.y = o1 - lse;
    ((float2*)out)[e] = res;
}

// ---------------------------------------------------------------------------
extern "C" void kernel_launch(void* const* d_in, const int* in_sizes, int n_in,
                              void* d_out, int out_size, void* d_ws, size_t ws_size,
                              hipStream_t stream)
{
    const float* x    = (const float*)d_in[0];
    const int*   ei   = (const int*)  d_in[1];
    const float* w1l  = (const float*)d_in[2];
    const float* b1l  = (const float*)d_in[3];
    const float* w1r  = (const float*)d_in[4];
    const float* w2l  = (const float*)d_in[5];
    const float* b2l  = (const float*)d_in[6];
    const float* w2r  = (const float*)d_in[7];
    const float* fc1w = (const float*)d_in[8];
    const float* fc1b = (const float*)d_in[9];
    const float* fc2w = (const float*)d_in[10];
    const float* fc2b = (const float*)d_in[11];
    float* out = (float*)d_out;

    int N = in_sizes[0] / NF;
    int E = in_sizes[1] / 2;
    const int* src = ei;
    const int* dst = ei + E;

    // ws layout: A16[N*16] h | B16[N*16] h | head[N] i32 | next2[E] int2
    // packed needs 2*N*32 + 4N + 8E bytes (~32.4 MB); fallback uses int next[E]
    __half* A16  = (__half*)d_ws;
    __half* B16  = A16 + (size_t)N * HID;
    int*    head = (int*)(B16 + (size_t)N * HID);
    void*   tail = (void*)(head + N);            // 8B-aligned for N*4 % 8 == 0

    size_t need_packed = (size_t)N * HID * 4 + (size_t)N * 4 + (size_t)E * 8;
    bool packed = (ws_size >= need_packed);

    int aggBlocks = (int)(((size_t)N * 8 + 255) / 256);

    init_head_kernel<<<(N + 255) / 256, 256, 0, stream>>>(head, N);

    if (packed) {
        int2* next2 = (int2*)tail;
        link_packed_kernel<<<(E + 255) / 256, 256, 0, stream>>>(src, dst, head, next2, E);

        gemm1_kernel<<<(N + 15) / 16, 256, 0, stream>>>(x, w1l, w1r, A16, B16, N);
        aggregate_packed_kernel<<<aggBlocks, 256, 0, stream>>>(head, next2, A16, B16, b1l, B16, N);

        gemm2_kernel<<<(N + 15) / 16, 256, 0, stream>>>(B16, w2l, w2r, A16, B16, N);
        aggregate_packed_kernel<<<aggBlocks, 256, 0, stream>>>(head, next2, A16, B16, b2l, B16, N);
    } else {
        int* next = (int*)tail;
        link_kernel<<<(E + 255) / 256, 256, 0, stream>>>(dst, head, next, E);

        gemm1_kernel<<<(N + 15) / 16, 256, 0, stream>>>(x, w1l, w1r, A16, B16, N);
        aggregate_chain_kernel<<<aggBlocks, 256, 0, stream>>>(head, next, src, A16, B16, b1l, B16, N);

        gemm2_kernel<<<(N + 15) / 16, 256, 0, stream>>>(B16, w2l, w2r, A16, B16, N);
        aggregate_chain_kernel<<<aggBlocks, 256, 0, stream>>>(head, next, src, A16, B16, b2l, B16, N);
    }

    edge_mlp_kernel<<<(E + 255) / 256, 256, 0, stream>>>(src, dst, B16, fc1w, fc1b,
                                                         fc2w, fc2b, out, E);
}